// Round 2
// baseline (475.447 us; speedup 1.0000x reference)
//
#include <hip/hip_runtime.h>
#include <hip/hip_fp16.h>

typedef unsigned short u16;
typedef unsigned int u32;

#define B_   256
#define T_   512
#define OBS_ 256
#define H_   128
#define G4_  512   // 4*H
#define LAT_ 16

typedef _Float16 half8_t __attribute__((ext_vector_type(8)));
typedef _Float16 half2_t __attribute__((ext_vector_type(2)));
typedef float    f32x4_t __attribute__((ext_vector_type(4)));

#if defined(__has_builtin)
#if __has_builtin(__builtin_amdgcn_fdot2)
#define HAVE_FDOT2 1
#endif
#endif

__device__ __forceinline__ u16 f2h(float x) { return __half_as_ushort(__float2half(x)); }
__device__ __forceinline__ float h2f(u16 u) { return __half2float(__ushort_as_half(u)); }
__device__ __forceinline__ float frcp(float x) { return __builtin_amdgcn_rcpf(x); }
__device__ __forceinline__ float fsigmoid(float x) { return frcp(1.f + __expf(-x)); }
__device__ __forceinline__ float ftanh(float x) { return 1.f - 2.f * frcp(1.f + __expf(2.f * x)); }

__device__ __forceinline__ float dot2acc(u32 w, u32 h, float acc) {
  half2_t wv = __builtin_bit_cast(half2_t, w);
  half2_t hv = __builtin_bit_cast(half2_t, h);
#ifdef HAVE_FDOT2
  return __builtin_amdgcn_fdot2(wv, hv, acc, false);
#else
  acc = fmaf((float)wv.x, (float)hv.x, acc);
  acc = fmaf((float)wv.y, (float)hv.y, acc);
  return acc;
#endif
}

// ---------------------------------------------------------------------------
// prep: Wxt16[n][k] = f16(Wx[k][n])   (512 x 256)
//       Whp[k2][j]  = pack(f16(Wh[2k2][j]), f16(Wh[2k2+1][j]))   (64 x 512)
// ---------------------------------------------------------------------------
__global__ __launch_bounds__(256) void prep_kernel(const float* __restrict__ Wx,
                                                   const float* __restrict__ Wh,
                                                   u16* __restrict__ Wxt,
                                                   u32* __restrict__ Whp) {
  int idx = blockIdx.x * 256 + threadIdx.x;
  if (idx < G4_ * OBS_) {
    int n = idx / OBS_, k = idx % OBS_;
    Wxt[idx] = f2h(Wx[(size_t)k * G4_ + n]);
  } else {
    int i2 = idx - G4_ * OBS_;
    if (i2 < (H_ / 2) * G4_) {
      int k2 = i2 / G4_, j = i2 % G4_;
      u32 lo = f2h(Wh[(size_t)(2 * k2) * G4_ + j]);
      u32 hi = f2h(Wh[(size_t)(2 * k2 + 1) * G4_ + j]);
      Whp[i2] = lo | (hi << 16);
    }
  }
}

// ---------------------------------------------------------------------------
// gemm_xw: Xw[m][n] = f16( sum_k xs_row(m)[k] * Wx[k][n] )  for a T-chunk.
// m = b*CT + tau  (chunk-local), xs row = b*T_ + t0 + tau.
// 64x64 tile, BK=64, 4 waves each computing a 32x32 quadrant via
// mfma_f32_16x16x32_f16 (A: lane m=l&15, k=(l>>4)*8+j ; B from Wxt[n][k]).
// ---------------------------------------------------------------------------
__global__ __launch_bounds__(256) void gemm_xw(const float* __restrict__ xs,
                                               const u16* __restrict__ Wxt,
                                               u16* __restrict__ Xw,
                                               int t0, int ct_log2) {
  __shared__ __align__(16) u16 As[64][72];
  __shared__ __align__(16) u16 Bs[64][72];

  const int tid  = threadIdx.x;
  const int lane = tid & 63;
  const int w    = tid >> 6;
  const int qr   = (w & 1) * 32;
  const int qc   = (w >> 1) * 32;
  const int bn   = blockIdx.x;   // 0..7
  const int bm   = blockIdx.y;

  f32x4_t acc[2][2];
#pragma unroll
  for (int a = 0; a < 2; ++a)
#pragma unroll
    for (int bq = 0; bq < 2; ++bq)
      acc[a][bq] = (f32x4_t){0.f, 0.f, 0.f, 0.f};

  const int row = tid >> 2;           // 0..63
  const int cb  = (tid & 3) * 16;     // 0,16,32,48
  const int m   = bm * 64 + row;
  const int bb  = m >> ct_log2;
  const int tau = m & ((1 << ct_log2) - 1);
  const float* asrc = xs + (size_t)(bb * T_ + t0 + tau) * OBS_;
  const u16*   bsrc = Wxt + (size_t)(bn * 64 + row) * OBS_;

  for (int k0 = 0; k0 < OBS_; k0 += 64) {
    {  // stage A (f32 -> f16)
      const float* s = asrc + k0 + cb;
      u32 uu[8];
#pragma unroll
      for (int u = 0; u < 4; ++u) {
        float4 v = *(const float4*)(s + u * 4);
        uu[u * 2 + 0] = (u32)f2h(v.x) | ((u32)f2h(v.y) << 16);
        uu[u * 2 + 1] = (u32)f2h(v.z) | ((u32)f2h(v.w) << 16);
      }
      *(uint4*)&As[row][cb]     = make_uint4(uu[0], uu[1], uu[2], uu[3]);
      *(uint4*)&As[row][cb + 8] = make_uint4(uu[4], uu[5], uu[6], uu[7]);
    }
    {  // stage B (already f16, Bs[n][k])
      const u16* s = bsrc + k0 + cb;
      uint4 v0 = *(const uint4*)(s);
      uint4 v1 = *(const uint4*)(s + 8);
      *(uint4*)&Bs[row][cb]     = v0;
      *(uint4*)&Bs[row][cb + 8] = v1;
    }
    __syncthreads();
#pragma unroll
    for (int ks = 0; ks < 2; ++ks) {
      const int kc = ks * 32 + (lane >> 4) * 8;
      half8_t a0 = *(const half8_t*)&As[qr + (lane & 15)][kc];
      half8_t a1 = *(const half8_t*)&As[qr + 16 + (lane & 15)][kc];
      half8_t b0 = *(const half8_t*)&Bs[qc + (lane & 15)][kc];
      half8_t b1 = *(const half8_t*)&Bs[qc + 16 + (lane & 15)][kc];
      acc[0][0] = __builtin_amdgcn_mfma_f32_16x16x32_f16(a0, b0, acc[0][0], 0, 0, 0);
      acc[0][1] = __builtin_amdgcn_mfma_f32_16x16x32_f16(a0, b1, acc[0][1], 0, 0, 0);
      acc[1][0] = __builtin_amdgcn_mfma_f32_16x16x32_f16(a1, b0, acc[1][0], 0, 0, 0);
      acc[1][1] = __builtin_amdgcn_mfma_f32_16x16x32_f16(a1, b1, acc[1][1], 0, 0, 0);
    }
    __syncthreads();
  }
  // D layout (verified): col = lane&15, row = (lane>>4)*4 + r
#pragma unroll
  for (int mi = 0; mi < 2; ++mi)
#pragma unroll
    for (int ni = 0; ni < 2; ++ni)
#pragma unroll
      for (int r = 0; r < 4; ++r) {
        int mm = bm * 64 + qr + mi * 16 + (lane >> 4) * 4 + r;
        int nn = bn * 64 + qc + ni * 16 + (lane & 15);
        Xw[(size_t)mm * G4_ + nn] = f2h(acc[mi][ni][r]);
      }
}

// ---------------------------------------------------------------------------
// lstm_rec: one block per batch row, 512 threads = one gate column each.
// Wh column lives in 64 VGPRs as packed f16 pairs; h broadcast via LDS.
// ---------------------------------------------------------------------------
__global__ __launch_bounds__(512) void lstm_rec(const u16* __restrict__ Xw,
                                                const u32* __restrict__ Whp,
                                                const float* __restrict__ bias,
                                                float* __restrict__ c_ws,
                                                u16* __restrict__ h_ws,
                                                int t0, int CT) {
  const int bb = blockIdx.x;
  const int j  = threadIdx.x;
  __shared__ uint4 hq[16];   // h as 128 packed f16
  __shared__ float g[512];

  u32 wh[64];
#pragma unroll
  for (int k2 = 0; k2 < 64; ++k2) wh[k2] = Whp[k2 * 512 + j];
  const float bj = bias[j];

  float c = 0.f;
  if (t0 == 0) {
    if (j < 16) hq[j] = make_uint4(0u, 0u, 0u, 0u);
  } else {
    if (j < 128) {
      ((u16*)hq)[j] = h_ws[bb * 128 + j];
      c = c_ws[bb * 128 + j];
    }
  }
  __syncthreads();

  const u16* xwp = Xw + (size_t)bb * CT * 512 + j;
  float xw_cur = h2f(xwp[0]);
  for (int t = 0; t < CT; ++t) {
    int tn = (t + 1 < CT) ? t + 1 : t;
    float xw_nxt = h2f(xwp[(size_t)tn * 512]);   // prefetch next step's input

    float a0 = 0.f, a1 = 0.f, a2 = 0.f, a3 = 0.f;
#pragma unroll
    for (int q = 0; q < 16; ++q) {
      uint4 hv = hq[q];                           // broadcast read
      a0 = dot2acc(wh[4 * q + 0], hv.x, a0);
      a1 = dot2acc(wh[4 * q + 1], hv.y, a1);
      a2 = dot2acc(wh[4 * q + 2], hv.z, a2);
      a3 = dot2acc(wh[4 * q + 3], hv.w, a3);
    }
    g[j] = ((a0 + a1) + (a2 + a3)) + bj + xw_cur;
    __syncthreads();
    if (j < 128) {
      float pi = g[j], pf = g[j + 128], pg = g[j + 256], po = g[j + 384];
      float ig = fsigmoid(pi);
      float fg = fsigmoid(pf);
      float gg = ftanh(pg);
      float og = fsigmoid(po);
      c = fg * c + ig * gg;
      float h = og * ftanh(c);
      ((u16*)hq)[j] = f2h(h);
    }
    __syncthreads();
    xw_cur = xw_nxt;
  }
  if (j < 128) {
    c_ws[bb * 128 + j] = c;
    h_ws[bb * 128 + j] = ((u16*)hq)[j];
  }
}

// ---------------------------------------------------------------------------
// head: out1 = relu(h @ W1 + b1); p = out1 @ W2 + b2; split mean/logvar.
// ---------------------------------------------------------------------------
__global__ __launch_bounds__(128) void head_kernel(const u16* __restrict__ h_ws,
                                                   const float* __restrict__ W1,
                                                   const float* __restrict__ b1,
                                                   const float* __restrict__ W2,
                                                   const float* __restrict__ b2,
                                                   float* __restrict__ out) {
  const int bb = blockIdx.x;
  const int j  = threadIdx.x;
  __shared__ float hs[128];
  __shared__ float o1[128];
  hs[j] = h2f(h_ws[bb * 128 + j]);
  __syncthreads();
  float acc = b1[j];
#pragma unroll 8
  for (int k = 0; k < 128; ++k) acc = fmaf(hs[k], W1[(size_t)k * 128 + j], acc);
  o1[j] = fmaxf(acc, 0.f);
  __syncthreads();
  if (j < 2 * LAT_) {
    float acc2 = b2[j];
#pragma unroll 8
    for (int k = 0; k < 128; ++k) acc2 = fmaf(o1[k], W2[(size_t)k * (2 * LAT_) + j], acc2);
    if (j < LAT_) out[(size_t)bb * LAT_ + j] = acc2;                       // mean
    else          out[(size_t)B_ * LAT_ + (size_t)bb * LAT_ + (j - LAT_)] = acc2;  // logvar
  }
}

// ---------------------------------------------------------------------------
extern "C" void kernel_launch(void* const* d_in, const int* in_sizes, int n_in,
                              void* d_out, int out_size, void* d_ws, size_t ws_size,
                              hipStream_t stream) {
  const float* xs   = (const float*)d_in[0];
  const float* Wx   = (const float*)d_in[1];
  const float* Wh   = (const float*)d_in[2];
  const float* bias = (const float*)d_in[3];
  const float* W1   = (const float*)d_in[4];
  const float* b1   = (const float*)d_in[5];
  const float* W2   = (const float*)d_in[6];
  const float* b2   = (const float*)d_in[7];
  float* out = (float*)d_out;

  char* ws = (char*)d_ws;
  u16* Wxt  = (u16*)(ws + 0);            // 512*256*2   = 262144
  u32* Whp  = (u32*)(ws + 262144);       // 64*512*4    = 131072
  float* c_ws = (float*)(ws + 393216);   // 256*128*4   = 131072
  u16* h_ws   = (u16*)(ws + 524288);     // 256*128*2   = 65536
  u16* Xw     = (u16*)(ws + 589824);     // 256*CT*512*2

  // largest power-of-two T-chunk that fits the workspace
  int CT = 512;
  while (CT > 8 && 589824 + (size_t)262144 * CT > ws_size) CT >>= 1;
  int ctl = __builtin_ctz((unsigned)CT);

  prep_kernel<<<640, 256, 0, stream>>>(Wx, Wh, Wxt, Whp);
  for (int t0 = 0; t0 < T_; t0 += CT) {
    gemm_xw<<<dim3(8, 4 * CT), 256, 0, stream>>>(xs, Wxt, Xw, t0, ctl);
    lstm_rec<<<256, 512, 0, stream>>>(Xw, Whp, bias, c_ws, h_ws, t0, CT);
  }
  head_kernel<<<256, 128, 0, stream>>>(h_ws, W1, b1, W2, b2, out);
}

// Round 3
// 440.684 us; speedup vs baseline: 1.0789x; 1.0789x over previous
//
#include <hip/hip_runtime.h>
#include <hip/hip_fp16.h>

typedef unsigned short u16;
typedef unsigned int u32;

#define B_   256
#define T_   512
#define OBS_ 256
#define H_   128
#define G4_  512   // 4*H
#define LAT_ 16

typedef _Float16 half8_t __attribute__((ext_vector_type(8)));
typedef _Float16 half2_t __attribute__((ext_vector_type(2)));
typedef float    f32x4_t __attribute__((ext_vector_type(4)));

#if defined(__has_builtin)
#if __has_builtin(__builtin_amdgcn_fdot2)
#define HAVE_FDOT2 1
#endif
#endif

__device__ __forceinline__ u16 f2h(float x) { return __half_as_ushort(__float2half(x)); }
__device__ __forceinline__ float h2f(u16 u) { return __half2float(__ushort_as_half(u)); }
__device__ __forceinline__ float frcp(float x) { return __builtin_amdgcn_rcpf(x); }
__device__ __forceinline__ float fsigmoid(float x) { return frcp(1.f + __expf(-x)); }
__device__ __forceinline__ float ftanh(float x) { return 1.f - 2.f * frcp(1.f + __expf(2.f * x)); }

__device__ __forceinline__ float dot2acc(u32 w, u32 h, float acc) {
  half2_t wv = __builtin_bit_cast(half2_t, w);
  half2_t hv = __builtin_bit_cast(half2_t, h);
#ifdef HAVE_FDOT2
  return __builtin_amdgcn_fdot2(wv, hv, acc, false);
#else
  acc = fmaf((float)wv.x, (float)hv.x, acc);
  acc = fmaf((float)wv.y, (float)hv.y, acc);
  return acc;
#endif
}

// ---------------------------------------------------------------------------
// prep: Wxt16[n][k] = f16(Wx[k][n])   (512 x 256)
//       Whp[k2][j]  = pack(f16(Wh[2k2][j]), f16(Wh[2k2+1][j]))   (64 x 512)
// ---------------------------------------------------------------------------
__global__ __launch_bounds__(256) void prep_kernel(const float* __restrict__ Wx,
                                                   const float* __restrict__ Wh,
                                                   u16* __restrict__ Wxt,
                                                   u32* __restrict__ Whp) {
  int idx = blockIdx.x * 256 + threadIdx.x;
  if (idx < G4_ * OBS_) {
    int n = idx / OBS_, k = idx % OBS_;
    Wxt[idx] = f2h(Wx[(size_t)k * G4_ + n]);
  } else {
    int i2 = idx - G4_ * OBS_;
    if (i2 < (H_ / 2) * G4_) {
      int k2 = i2 / G4_, j = i2 % G4_;
      u32 lo = f2h(Wh[(size_t)(2 * k2) * G4_ + j]);
      u32 hi = f2h(Wh[(size_t)(2 * k2 + 1) * G4_ + j]);
      Whp[i2] = lo | (hi << 16);
    }
  }
}

// ---------------------------------------------------------------------------
// gemm_xw: Xw[m][n] = f16( sum_k xs_row(m)[k] * Wx[k][n] )  for a T-chunk.
// m = b*CT + tau (chunk-local); xs row = b*T_ + t0 + tau.
// 128x128 tile, BK=64, 4 waves, each wave a 64x64 quadrant = 4x4 frags of
// mfma_f32_16x16x32_f16. LDS pad: [..][88] -> row stride 176 B (16B aligned,
// banks tile 32 with 2-way aliasing = free).
// ---------------------------------------------------------------------------
__global__ __launch_bounds__(256, 2) void gemm_xw(const float* __restrict__ xs,
                                                  const u16* __restrict__ Wxt,
                                                  u16* __restrict__ Xw,
                                                  int t0, int ct_log2) {
  __shared__ __align__(16) u16 As[128][88];
  __shared__ __align__(16) u16 Bs[128][88];

  const int tid  = threadIdx.x;
  const int lane = tid & 63;
  const int w    = tid >> 6;
  const int qr   = (w & 1) * 64;
  const int qc   = (w >> 1) * 64;
  const int bn   = blockIdx.x;   // 0..3  (n-tile of 128)
  const int bm   = blockIdx.y;   // m-tile of 128

  f32x4_t acc[4][4];
#pragma unroll
  for (int a = 0; a < 4; ++a)
#pragma unroll
    for (int bq = 0; bq < 4; ++bq)
      acc[a][bq] = (f32x4_t){0.f, 0.f, 0.f, 0.f};

  // staging assignment: 2 threads per row, 32 k-elements each
  const int row  = tid >> 1;          // 0..127
  const int half = (tid & 1) * 32;    // 0 or 32
  const int m    = bm * 128 + row;
  const int bb   = m >> ct_log2;
  const int tau  = m & ((1 << ct_log2) - 1);
  const float* asrc = xs + (size_t)(bb * T_ + t0 + tau) * OBS_ + half;
  const u16*   bsrc = Wxt + (size_t)(bn * 128 + row) * OBS_ + half;

  for (int k0 = 0; k0 < OBS_; k0 += 64) {
    {  // stage A (f32 -> f16), 32 vals/thread = 4 x ds_write_b128
      const float* s = asrc + k0;
#pragma unroll
      for (int i = 0; i < 4; ++i) {
        float4 v0 = *(const float4*)(s + i * 8);
        float4 v1 = *(const float4*)(s + i * 8 + 4);
        uint4 pk;
        pk.x = (u32)f2h(v0.x) | ((u32)f2h(v0.y) << 16);
        pk.y = (u32)f2h(v0.z) | ((u32)f2h(v0.w) << 16);
        pk.z = (u32)f2h(v1.x) | ((u32)f2h(v1.y) << 16);
        pk.w = (u32)f2h(v1.z) | ((u32)f2h(v1.w) << 16);
        *(uint4*)&As[row][half + i * 8] = pk;
      }
    }
    {  // stage B (already f16)
      const u16* s = bsrc + k0;
#pragma unroll
      for (int i = 0; i < 4; ++i)
        *(uint4*)&Bs[row][half + i * 8] = *(const uint4*)(s + i * 8);
    }
    __syncthreads();
#pragma unroll
    for (int ks = 0; ks < 2; ++ks) {
      const int kc = ks * 32 + (lane >> 4) * 8;
      half8_t af[4], bf[4];
#pragma unroll
      for (int mi = 0; mi < 4; ++mi) af[mi] = *(const half8_t*)&As[qr + mi * 16 + (lane & 15)][kc];
#pragma unroll
      for (int ni = 0; ni < 4; ++ni) bf[ni] = *(const half8_t*)&Bs[qc + ni * 16 + (lane & 15)][kc];
#pragma unroll
      for (int mi = 0; mi < 4; ++mi)
#pragma unroll
        for (int ni = 0; ni < 4; ++ni)
          acc[mi][ni] = __builtin_amdgcn_mfma_f32_16x16x32_f16(af[mi], bf[ni], acc[mi][ni], 0, 0, 0);
    }
    __syncthreads();
  }
  // D layout: col = lane&15, row = (lane>>4)*4 + r
#pragma unroll
  for (int mi = 0; mi < 4; ++mi)
#pragma unroll
    for (int ni = 0; ni < 4; ++ni)
#pragma unroll
      for (int r = 0; r < 4; ++r) {
        int mm = bm * 128 + qr + mi * 16 + (lane >> 4) * 4 + r;
        int nn = bn * 128 + qc + ni * 16 + (lane & 15);
        Xw[(size_t)mm * G4_ + nn] = f2h(acc[mi][ni][r]);
      }
}

// ---------------------------------------------------------------------------
// lstm_rec: one block per batch row, 512 threads = one gate column each.
// Wh column lives in 64 VGPRs as packed f16 pairs; h broadcast via LDS.
// __launch_bounds__(512, 1): grid is exactly 1 block/CU -> grant full VGPR
// budget so wh[64] stays in registers (R2 fix: was 44 VGPRs -> spilled).
// ---------------------------------------------------------------------------
__global__ __launch_bounds__(512, 1) void lstm_rec(const u16* __restrict__ Xw,
                                                   const u32* __restrict__ Whp,
                                                   const float* __restrict__ bias,
                                                   float* __restrict__ c_ws,
                                                   u16* __restrict__ h_ws,
                                                   int t0, int CT) {
  const int bb = blockIdx.x;
  const int j  = threadIdx.x;
  __shared__ uint4 hq[16];   // h as 128 packed f16
  __shared__ float g[512];

  u32 wh[64];
#pragma unroll
  for (int k2 = 0; k2 < 64; ++k2) wh[k2] = Whp[k2 * 512 + j];
  const float bj = bias[j];

  float c = 0.f;
  if (t0 == 0) {
    if (j < 16) hq[j] = make_uint4(0u, 0u, 0u, 0u);
  } else {
    if (j < 128) {
      ((u16*)hq)[j] = h_ws[bb * 128 + j];
      c = c_ws[bb * 128 + j];
    }
  }
  __syncthreads();

  const u16* xwp = Xw + (size_t)bb * CT * 512 + j;
  float xw_cur = h2f(xwp[0]);
  for (int t = 0; t < CT; ++t) {
    int tn = (t + 1 < CT) ? t + 1 : t;
    float xw_nxt = h2f(xwp[(size_t)tn * 512]);   // prefetch next step's input

    float a0 = 0.f, a1 = 0.f, a2 = 0.f, a3 = 0.f;
#pragma unroll
    for (int q = 0; q < 16; ++q) {
      uint4 hv = hq[q];                           // broadcast read
      a0 = dot2acc(wh[4 * q + 0], hv.x, a0);
      a1 = dot2acc(wh[4 * q + 1], hv.y, a1);
      a2 = dot2acc(wh[4 * q + 2], hv.z, a2);
      a3 = dot2acc(wh[4 * q + 3], hv.w, a3);
    }
    g[j] = ((a0 + a1) + (a2 + a3)) + bj + xw_cur;
    __syncthreads();
    if (j < 128) {
      float pi = g[j], pf = g[j + 128], pg = g[j + 256], po = g[j + 384];
      float ig = fsigmoid(pi);
      float fg = fsigmoid(pf);
      float gg = ftanh(pg);
      float og = fsigmoid(po);
      c = fg * c + ig * gg;
      float h = og * ftanh(c);
      ((u16*)hq)[j] = f2h(h);
    }
    __syncthreads();
    xw_cur = xw_nxt;
  }
  if (j < 128) {
    c_ws[bb * 128 + j] = c;
    h_ws[bb * 128 + j] = ((u16*)hq)[j];
  }
}

// ---------------------------------------------------------------------------
// head: out1 = relu(h @ W1 + b1); p = out1 @ W2 + b2; split mean/logvar.
// ---------------------------------------------------------------------------
__global__ __launch_bounds__(128) void head_kernel(const u16* __restrict__ h_ws,
                                                   const float* __restrict__ W1,
                                                   const float* __restrict__ b1,
                                                   const float* __restrict__ W2,
                                                   const float* __restrict__ b2,
                                                   float* __restrict__ out) {
  const int bb = blockIdx.x;
  const int j  = threadIdx.x;
  __shared__ float hs[128];
  __shared__ float o1[128];
  hs[j] = h2f(h_ws[bb * 128 + j]);
  __syncthreads();
  float acc = b1[j];
#pragma unroll 8
  for (int k = 0; k < 128; ++k) acc = fmaf(hs[k], W1[(size_t)k * 128 + j], acc);
  o1[j] = fmaxf(acc, 0.f);
  __syncthreads();
  if (j < 2 * LAT_) {
    float acc2 = b2[j];
#pragma unroll 8
    for (int k = 0; k < 128; ++k) acc2 = fmaf(o1[k], W2[(size_t)k * (2 * LAT_) + j], acc2);
    if (j < LAT_) out[(size_t)bb * LAT_ + j] = acc2;                       // mean
    else          out[(size_t)B_ * LAT_ + (size_t)bb * LAT_ + (j - LAT_)] = acc2;  // logvar
  }
}

// ---------------------------------------------------------------------------
extern "C" void kernel_launch(void* const* d_in, const int* in_sizes, int n_in,
                              void* d_out, int out_size, void* d_ws, size_t ws_size,
                              hipStream_t stream) {
  const float* xs   = (const float*)d_in[0];
  const float* Wx   = (const float*)d_in[1];
  const float* Wh   = (const float*)d_in[2];
  const float* bias = (const float*)d_in[3];
  const float* W1   = (const float*)d_in[4];
  const float* b1   = (const float*)d_in[5];
  const float* W2   = (const float*)d_in[6];
  const float* b2   = (const float*)d_in[7];
  float* out = (float*)d_out;

  char* ws = (char*)d_ws;
  u16* Wxt  = (u16*)(ws + 0);            // 512*256*2   = 262144
  u32* Whp  = (u32*)(ws + 262144);       // 64*512*4    = 131072
  float* c_ws = (float*)(ws + 393216);   // 256*128*4   = 131072
  u16* h_ws   = (u16*)(ws + 524288);     // 256*128*2   = 65536
  u16* Xw     = (u16*)(ws + 589824);     // 256*CT*512*2

  // largest power-of-two T-chunk that fits the workspace (>=128 for gemm tiles)
  int CT = 512;
  while (CT > 128 && 589824 + (size_t)262144 * CT > ws_size) CT >>= 1;
  int ctl = __builtin_ctz((unsigned)CT);

  prep_kernel<<<640, 256, 0, stream>>>(Wx, Wh, Wxt, Whp);
  for (int t0 = 0; t0 < T_; t0 += CT) {
    gemm_xw<<<dim3(4, 2 * CT), 256, 0, stream>>>(xs, Wxt, Xw, t0, ctl);
    lstm_rec<<<256, 512, 0, stream>>>(Xw, Whp, bias, c_ws, h_ws, t0, CT);
  }
  head_kernel<<<256, 128, 0, stream>>>(h_ws, W1, b1, W2, b2, out);
}